// Round 2
// baseline (878.861 us; speedup 1.0000x reference)
//
#include <hip/hip_runtime.h>
#include <hip/hip_bf16.h>
#include <math.h>

// Problem constants
#define BB      256
#define I_DIM   256
#define H_DIM   512
#define A_DIM   400
#define V_DIM   50000
#define OOV     50
#define VP      50050   // V + OOV
#define FC1_IN  912     // A + H
#define FC1_OUT 1024    // 2H
#define FC2_K   1024

typedef unsigned short u16;
typedef unsigned int   u32;
typedef __attribute__((ext_vector_type(8))) short  short8;
typedef __attribute__((ext_vector_type(4))) float  float4_;

__device__ __forceinline__ u16 f2bf(float f) {
    u32 u = __builtin_bit_cast(u32, f);
    u32 r = (u + 0x7FFFu + ((u >> 16) & 1u)) >> 16;   // RNE
    return (u16)r;
}

// ---------------- Generic small fp32 GEMM: C[M,N] = A[M,K] @ W[N,K]^T ----------------
// 32x32 tile, BK=16, 256 threads, 2x2 micro-tile. N-guard only (M%32==0, K%16==0).
__global__ __launch_bounds__(256)
void sgemm32(const float* __restrict__ Am, const float* __restrict__ Wm,
             float* __restrict__ Cm, const float* __restrict__ bias0,
             const float* __restrict__ bias1, int M, int N, int K,
             int accumulate, int act)
{
    __shared__ float As[16][33];
    __shared__ float Bs[16][33];
    int t  = threadIdx.x;
    int tx = t & 15, ty = t >> 4;
    int m0 = blockIdx.y * 32, n0 = blockIdx.x * 32;
    int lm = t >> 3;           // 0..31
    int lk = (t & 7) * 2;      // 0..14
    const float* aptr = Am + (size_t)(m0 + lm) * K + lk;
    const float* wptr = Wm + (size_t)(n0 + lm) * K + lk;
    bool wvalid = (n0 + lm) < N;
    float c00 = 0.f, c01 = 0.f, c10 = 0.f, c11 = 0.f;

    for (int k0 = 0; k0 < K; k0 += 16) {
        float a0 = aptr[0], a1 = aptr[1];
        float w0 = wvalid ? wptr[0] : 0.f;
        float w1 = wvalid ? wptr[1] : 0.f;
        __syncthreads();
        As[lk][lm] = a0;  As[lk + 1][lm] = a1;
        Bs[lk][lm] = w0;  Bs[lk + 1][lm] = w1;
        __syncthreads();
#pragma unroll
        for (int k = 0; k < 16; ++k) {
            float av0 = As[k][ty], av1 = As[k][ty + 16];
            float bv0 = Bs[k][tx], bv1 = Bs[k][tx + 16];
            c00 += av0 * bv0;  c01 += av0 * bv1;
            c10 += av1 * bv0;  c11 += av1 * bv1;
        }
        aptr += 16; wptr += 16;
    }

    int r0 = m0 + ty, r1 = m0 + ty + 16;
    int cc0 = n0 + tx, cc1 = n0 + tx + 16;
    float accv[2][2] = {{c00, c01}, {c10, c11}};
    int rows[2] = {r0, r1};
    int cols[2] = {cc0, cc1};
#pragma unroll
    for (int i = 0; i < 2; ++i)
#pragma unroll
        for (int j = 0; j < 2; ++j) {
            int c = cols[j];
            if (c < N) {
                size_t idx = (size_t)rows[i] * N + c;
                float v = accv[i][j];
                if (accumulate) v += Cm[idx];
                if (bias0) v += bias0[c];
                if (bias1) v += bias1[c];
                if (act == 1) v = tanhf(v);
                Cm[idx] = v;
            }
        }
}

// ---------------- LSTM pointwise: c = sig(i)*tanh(g); h = sig(o)*tanh(c) ----------------
__global__ __launch_bounds__(256)
void lstm_h_kernel(const float* __restrict__ G, float* __restrict__ hbuf,
                   float* __restrict__ dec_in)
{
    int idx = blockIdx.x * 256 + threadIdx.x;     // 256*512
    int b = idx >> 9, j = idx & 511;
    const float* g = G + (size_t)b * 2048;
    float ig = g[j], gg = g[1024 + j], og = g[1536 + j];
    float si = 1.f / (1.f + expf(-ig));
    float so = 1.f / (1.f + expf(-og));
    float c  = si * tanhf(gg);
    float h  = so * tanhf(c);
    hbuf[idx] = h;
    dec_in[(size_t)b * FC1_IN + A_DIM + j] = h;
}

// ---------------- attention = v * softmax(e) per row ----------------
__global__ __launch_bounds__(256)
void att_kernel(const float* __restrict__ e, const float* __restrict__ vvec,
                float* __restrict__ att)
{
    __shared__ float s_ex[A_DIM];
    __shared__ float red[256];
    int b = blockIdx.x, t = threadIdx.x;
    const float* er = e + (size_t)b * A_DIM;
    float local = 0.f;
    for (int a = t; a < A_DIM; a += 256) {
        float ex = expf(er[a]);     // |e|<1 after tanh: no max-sub needed
        s_ex[a] = ex; local += ex;
    }
    red[t] = local; __syncthreads();
    for (int s = 128; s > 0; s >>= 1) {
        if (t < s) red[t] += red[t + s];
        __syncthreads();
    }
    float inv = 1.f / red[0];
    for (int a = t; a < A_DIM; a += 256)
        att[(size_t)b * A_DIM + a] = vvec[a] * s_ex[a] * inv;
}

// ---------------- context = att @ enc  (+ gen reduction) ----------------
__global__ __launch_bounds__(512)
void ctx_gen_kernel(const float* __restrict__ att, const float* __restrict__ enc,
                    const float* __restrict__ x, const float* __restrict__ h,
                    const float* __restrict__ pg1, const float* __restrict__ pg2,
                    const float* __restrict__ pg3,
                    float* __restrict__ dec_in, float* __restrict__ gen)
{
    __shared__ float s_att[A_DIM];
    __shared__ float red[512];
    int b = blockIdx.x, t = threadIdx.x;
    for (int a = t; a < A_DIM; a += 512) s_att[a] = att[(size_t)b * A_DIM + a];
    __syncthreads();
    float acc = 0.f;
    if (t < A_DIM) {
        const float* ep = enc + (size_t)b * (A_DIM * A_DIM) + t;
#pragma unroll 4
        for (int a = 0; a < A_DIM; ++a) acc += s_att[a] * ep[(size_t)a * A_DIM];
        dec_in[(size_t)b * FC1_IN + t] = acc;
    }
    float local = 0.f;
    if (t < A_DIM) local += acc * pg2[t];
    if (t < I_DIM) local += x[(size_t)b * I_DIM + t] * pg1[t];
    local += h[(size_t)b * H_DIM + t] * pg3[t];     // t < 512 always
    red[t] = local; __syncthreads();
    for (int s = 256; s > 0; s >>= 1) {
        if (t < s) red[t] += red[t + s];
        __syncthreads();
    }
    if (t == 0) gen[b] = 1.f / (1.f + expf(-red[0]));
}

// ---------------- hid fp32 -> bf16 ----------------
__global__ __launch_bounds__(256)
void cvt_kernel(const float* __restrict__ hid, u16* __restrict__ hb)
{
    int idx = blockIdx.x * 256 + threadIdx.x;     // 256*1024
    hb[idx] = f2bf(hid[idx]);
}

// ---------------- fc2 via bf16 MFMA + exp + row-sum atomics ----------------
// BARRIER-FREE / LDS-FREE version. Theory: the per-K-tile __syncthreads() +
// implicit vmcnt(0) drain convoyed all 24 waves/CU on the tail latency of the
// W loads every tile (measured in-flight bytes ~= 1 tile of loads -> 15.8 GB/s/CU).
// Now each wave loads its own B-fragments (fp32 W -> in-reg cvt to bf16) with
// all 20 loads of a tile batched and independent; the 8x W re-read across the
// block's waves is absorbed by L1 (16KB tile < 32KB L1) and L3 (W = 205MB < 256MB).
// 512 thr = 8 waves; wave owns 32 rows x 64 cols; K=1024, 16 tiles of 64.
__global__ __launch_bounds__(512)
void fc2_kernel(const u16* __restrict__ hb, const float* __restrict__ W,
                const float* __restrict__ bias, float* __restrict__ out,
                float* __restrict__ sums)
{
    int t = threadIdx.x;
    int wv = t >> 6, lane = t & 63;               // wv 0..7
    int lm = lane & 15, lk = lane >> 4;           // 0..15, 0..3
    int n0 = blockIdx.x * 64;
    int row_base = wv * 32;

    float4_ acc[2][4];
#pragma unroll
    for (int mi = 0; mi < 2; ++mi)
#pragma unroll
        for (int ni = 0; ni < 4; ++ni)
            acc[mi][ni] = (float4_){0.f, 0.f, 0.f, 0.f};

    // A row pointers (bf16, K-contiguous)
    const u16* a0 = hb + (size_t)(row_base + lm) * FC2_K + lk * 8;
    const u16* a1 = a0 + (size_t)16 * FC2_K;

    // W row pointers per ni (fp32, K-contiguous); tail guard per ni
    const float* wp0, *wp1, *wp2, *wp3;
    bool ok0, ok1, ok2, ok3;
    {
        int r0 = n0 + 0 * 16 + lm, r1 = n0 + 1 * 16 + lm;
        int r2 = n0 + 2 * 16 + lm, r3 = n0 + 3 * 16 + lm;
        ok0 = r0 < V_DIM; ok1 = r1 < V_DIM; ok2 = r2 < V_DIM; ok3 = r3 < V_DIM;
        wp0 = W + (size_t)(ok0 ? r0 : 0) * FC2_K + lk * 8;
        wp1 = W + (size_t)(ok1 ? r1 : 0) * FC2_K + lk * 8;
        wp2 = W + (size_t)(ok2 ? r2 : 0) * FC2_K + lk * 8;
        wp3 = W + (size_t)(ok3 ? r3 : 0) * FC2_K + lk * 8;
    }

#pragma unroll 1
    for (int kt = 0; kt < FC2_K / 64; ++kt) {
        int kb = kt * 64;
        // ---- batch-issue ALL loads of this tile (independent; stay in flight) ----
        float4_ w00a, w00b, w01a, w01b;   // ni=0, ks=0/1, halves a/b
        float4_ w10a, w10b, w11a, w11b;   // ni=1
        float4_ w20a, w20b, w21a, w21b;   // ni=2
        float4_ w30a, w30b, w31a, w31b;   // ni=3
        {
            const float4_ z = (float4_){0.f, 0.f, 0.f, 0.f};
            const float4_* p0 = (const float4_*)(wp0 + kb);
            const float4_* p1 = (const float4_*)(wp1 + kb);
            const float4_* p2 = (const float4_*)(wp2 + kb);
            const float4_* p3 = (const float4_*)(wp3 + kb);
            w00a = ok0 ? p0[0] : z;  w00b = ok0 ? p0[1] : z;
            w01a = ok0 ? p0[2] : z;  w01b = ok0 ? p0[3] : z;
            w10a = ok1 ? p1[0] : z;  w10b = ok1 ? p1[1] : z;
            w11a = ok1 ? p1[2] : z;  w11b = ok1 ? p1[3] : z;
            w20a = ok2 ? p2[0] : z;  w20b = ok2 ? p2[1] : z;
            w21a = ok2 ? p2[2] : z;  w21b = ok2 ? p2[3] : z;
            w30a = ok3 ? p3[0] : z;  w30b = ok3 ? p3[1] : z;
            w31a = ok3 ? p3[2] : z;  w31b = ok3 ? p3[3] : z;
        }
        short8 af[2][2];
        af[0][0] = *(const short8*)(a0 + kb);
        af[0][1] = *(const short8*)(a0 + kb + 32);
        af[1][0] = *(const short8*)(a1 + kb);
        af[1][1] = *(const short8*)(a1 + kb + 32);

        // ---- cvt + MFMA, ks = 0 ----
        {
            short8 b0, b1, b2, b3;
#pragma unroll
            for (int i = 0; i < 4; ++i) {
                b0[i] = (short)f2bf(w00a[i]);  b0[4 + i] = (short)f2bf(w00b[i]);
                b1[i] = (short)f2bf(w10a[i]);  b1[4 + i] = (short)f2bf(w10b[i]);
                b2[i] = (short)f2bf(w20a[i]);  b2[4 + i] = (short)f2bf(w20b[i]);
                b3[i] = (short)f2bf(w30a[i]);  b3[4 + i] = (short)f2bf(w30b[i]);
            }
#pragma unroll
            for (int mi = 0; mi < 2; ++mi) {
                acc[mi][0] = __builtin_amdgcn_mfma_f32_16x16x32_bf16(af[mi][0], b0, acc[mi][0], 0, 0, 0);
                acc[mi][1] = __builtin_amdgcn_mfma_f32_16x16x32_bf16(af[mi][0], b1, acc[mi][1], 0, 0, 0);
                acc[mi][2] = __builtin_amdgcn_mfma_f32_16x16x32_bf16(af[mi][0], b2, acc[mi][2], 0, 0, 0);
                acc[mi][3] = __builtin_amdgcn_mfma_f32_16x16x32_bf16(af[mi][0], b3, acc[mi][3], 0, 0, 0);
            }
        }
        // ---- cvt + MFMA, ks = 1 ----
        {
            short8 b0, b1, b2, b3;
#pragma unroll
            for (int i = 0; i < 4; ++i) {
                b0[i] = (short)f2bf(w01a[i]);  b0[4 + i] = (short)f2bf(w01b[i]);
                b1[i] = (short)f2bf(w11a[i]);  b1[4 + i] = (short)f2bf(w11b[i]);
                b2[i] = (short)f2bf(w21a[i]);  b2[4 + i] = (short)f2bf(w21b[i]);
                b3[i] = (short)f2bf(w31a[i]);  b3[4 + i] = (short)f2bf(w31b[i]);
            }
#pragma unroll
            for (int mi = 0; mi < 2; ++mi) {
                acc[mi][0] = __builtin_amdgcn_mfma_f32_16x16x32_bf16(af[mi][1], b0, acc[mi][0], 0, 0, 0);
                acc[mi][1] = __builtin_amdgcn_mfma_f32_16x16x32_bf16(af[mi][1], b1, acc[mi][1], 0, 0, 0);
                acc[mi][2] = __builtin_amdgcn_mfma_f32_16x16x32_bf16(af[mi][1], b2, acc[mi][2], 0, 0, 0);
                acc[mi][3] = __builtin_amdgcn_mfma_f32_16x16x32_bf16(af[mi][1], b3, acc[mi][3], 0, 0, 0);
            }
        }
    }

    // Epilogue: logit = acc + bias; e = exp(logit); store; row-sum via shfl + atomic.
#pragma unroll
    for (int mi = 0; mi < 2; ++mi) {
        int r_base = row_base + mi * 16 + lk * 4;   // rows r_base..r_base+3
        float s[4] = {0.f, 0.f, 0.f, 0.f};
#pragma unroll
        for (int ni = 0; ni < 4; ++ni) {
            int col = n0 + ni * 16 + lm;
            if (col < V_DIM) {
                float bcol = bias[col];
                float4_ a = acc[mi][ni];
#pragma unroll
                for (int r = 0; r < 4; ++r) {
                    float ev = expf(a[r] + bcol);
                    out[(size_t)(r_base + r) * VP + col] = ev;
                    s[r] += ev;
                }
            }
        }
#pragma unroll
        for (int off = 1; off < 16; off <<= 1) {
#pragma unroll
            for (int r = 0; r < 4; ++r) s[r] += __shfl_xor(s[r], off);
        }
        if (lm == 0) {
#pragma unroll
            for (int r = 0; r < 4; ++r) atomicAdd(&sums[r_base + r], s[r]);
        }
    }
}

// ---------------- out = gen/sum * exp ; zero OOV tail ----------------
__global__ __launch_bounds__(256)
void rescale_kernel(float* __restrict__ out, const float* __restrict__ gen,
                    const float* __restrict__ sums)
{
    int idx = (blockIdx.x * 256 + threadIdx.x) * 2;   // total 256*50050, even
    int b = idx / VP;
    int c = idx - b * VP;
    float2 v = *(float2*)(out + idx);
    float scale = gen[b] / sums[b];
    v.x = (c     < V_DIM) ? v.x * scale : 0.f;
    v.y = (c + 1 < V_DIM) ? v.y * scale : 0.f;
    *(float2*)(out + idx) = v;
}

// ---------------- scatter: out[b, ids[b,a]] += (1-gen[b]) * att[b,a] ----------------
__global__ __launch_bounds__(256)
void scatter_kernel(const int* __restrict__ ids, const float* __restrict__ att,
                    const float* __restrict__ gen, float* __restrict__ out)
{
    int idx = blockIdx.x * 256 + threadIdx.x;   // 256*400
    int b = idx / A_DIM;
    float val = (1.f - gen[b]) * att[idx];
    atomicAdd(out + (size_t)b * VP + ids[idx], val);
}

extern "C" void kernel_launch(void* const* d_in, const int* in_sizes, int n_in,
                              void* d_out, int out_size, void* d_ws, size_t ws_size,
                              hipStream_t stream)
{
    const float* x         = (const float*)d_in[0];
    const float* enc       = (const float*)d_in[2];
    const float* enc_state = (const float*)d_in[4];
    const int*   ids       = (const int*)  d_in[6];
    const float* W_ih      = (const float*)d_in[7];
    const float* b_ih      = (const float*)d_in[9];
    const float* b_hh      = (const float*)d_in[10];
    const float* Wh_w      = (const float*)d_in[11];
    const float* Wh_b      = (const float*)d_in[12];
    const float* Ws_w      = (const float*)d_in[13];
    const float* Ws_b      = (const float*)d_in[14];
    const float* vvec      = (const float*)d_in[15];
    const float* fc1_w     = (const float*)d_in[16];
    const float* fc1_b     = (const float*)d_in[17];
    const float* fc2_w     = (const float*)d_in[18];
    const float* fc2_b     = (const float*)d_in[19];
    const float* pg1       = (const float*)d_in[20];
    const float* pg2       = (const float*)d_in[21];
    const float* pg3       = (const float*)d_in[22];
    float* out = (float*)d_out;

    float* ws    = (float*)d_ws;
    float* gates = ws;                        // 256*2048
    float* hbuf  = gates + 256 * 2048;        // 256*512
    float* ebuf  = hbuf  + 256 * 512;         // 256*400
    float* attb  = ebuf  + 256 * 400;         // 256*400
    float* dec   = attb  + 256 * 400;         // 256*912
    float* hid   = dec   + 256 * 912;         // 256*1024
    float* genb  = hid   + 256 * 1024;        // 256
    float* sums  = genb  + 256;               // 256
    u16*   hbf   = (u16*)(sums + 256);        // 256*1024 bf16

    // gates = x0 @ W_ih^T + b_ih + b_hh
    sgemm32<<<dim3(64, 8), 256, 0, stream>>>(x, W_ih, gates, b_ih, b_hh,
                                             BB, 2048, I_DIM, 0, 0);
    // h
    lstm_h_kernel<<<512, 256, 0, stream>>>(gates, hbuf, dec);
    // e = tanh(ES@Wh^T + Wh_b + h@Ws^T + Ws_b)
    sgemm32<<<dim3(13, 8), 256, 0, stream>>>(enc_state, Wh_w, ebuf, Wh_b, nullptr,
                                             BB, A_DIM, H_DIM, 0, 0);
    sgemm32<<<dim3(13, 8), 256, 0, stream>>>(hbuf, Ws_w, ebuf, Ws_b, nullptr,
                                             BB, A_DIM, H_DIM, 1, 1);
    // attention
    att_kernel<<<BB, 256, 0, stream>>>(ebuf, vvec, attb);
    // context + gen
    ctx_gen_kernel<<<BB, 512, 0, stream>>>(attb, enc, x, hbuf, pg1, pg2, pg3,
                                           dec, genb);
    // fc1
    sgemm32<<<dim3(32, 8), 256, 0, stream>>>(dec, fc1_w, hid, fc1_b, nullptr,
                                             BB, FC1_OUT, FC1_IN, 0, 0);
    // hid -> bf16
    cvt_kernel<<<1024, 256, 0, stream>>>(hid, hbf);
    // zero row sums
    hipMemsetAsync(sums, 0, BB * sizeof(float), stream);
    // fc2 + exp + row sums  (782 = ceil(50000/64))
    fc2_kernel<<<782, 512, 0, stream>>>(hbf, fc2_w, fc2_b, out, sums);
    // scale by gen/sum, zero OOV tail
    rescale_kernel<<<(BB * VP) / 512, 256, 0, stream>>>(out, genb, sums);
    // pointer-copy scatter
    scatter_kernel<<<(BB * A_DIM) / 256, 256, 0, stream>>>(ids, attb, genb, out);
}

// Round 3
// 705.461 us; speedup vs baseline: 1.2458x; 1.2458x over previous
//
#include <hip/hip_runtime.h>
#include <hip/hip_bf16.h>
#include <math.h>

// Problem constants
#define BB      256
#define I_DIM   256
#define H_DIM   512
#define A_DIM   400
#define V_DIM   50000
#define OOV     50
#define VP      50050   // V + OOV
#define FC1_IN  912     // A + H
#define FC1_OUT 1024    // 2H
#define FC2_K   1024

typedef unsigned short u16;
typedef unsigned int   u32;
typedef __attribute__((ext_vector_type(8))) short  short8;
typedef __attribute__((ext_vector_type(4))) float  float4_;

__device__ __forceinline__ u16 f2bf(float f) {
    u32 u = __builtin_bit_cast(u32, f);
    u32 r = (u + 0x7FFFu + ((u >> 16) & 1u)) >> 16;   // RNE
    return (u16)r;
}

__device__ __forceinline__ short8 cvt_pack8(float4_ a, float4_ b) {
    short8 r;
#pragma unroll
    for (int i = 0; i < 4; ++i) {
        r[i]     = (short)f2bf(a[i]);
        r[4 + i] = (short)f2bf(b[i]);
    }
    return r;
}

// ---------------- Generic small fp32 GEMM: C[M,N] = A[M,K] @ W[N,K]^T ----------------
// 32x32 tile, BK=16, 256 threads, 2x2 micro-tile. N-guard only (M%32==0, K%16==0).
__global__ __launch_bounds__(256)
void sgemm32(const float* __restrict__ Am, const float* __restrict__ Wm,
             float* __restrict__ Cm, const float* __restrict__ bias0,
             const float* __restrict__ bias1, int M, int N, int K,
             int accumulate, int act)
{
    __shared__ float As[16][33];
    __shared__ float Bs[16][33];
    int t  = threadIdx.x;
    int tx = t & 15, ty = t >> 4;
    int m0 = blockIdx.y * 32, n0 = blockIdx.x * 32;
    int lm = t >> 3;           // 0..31
    int lk = (t & 7) * 2;      // 0..14
    const float* aptr = Am + (size_t)(m0 + lm) * K + lk;
    const float* wptr = Wm + (size_t)(n0 + lm) * K + lk;
    bool wvalid = (n0 + lm) < N;
    float c00 = 0.f, c01 = 0.f, c10 = 0.f, c11 = 0.f;

    for (int k0 = 0; k0 < K; k0 += 16) {
        float a0 = aptr[0], a1 = aptr[1];
        float w0 = wvalid ? wptr[0] : 0.f;
        float w1 = wvalid ? wptr[1] : 0.f;
        __syncthreads();
        As[lk][lm] = a0;  As[lk + 1][lm] = a1;
        Bs[lk][lm] = w0;  Bs[lk + 1][lm] = w1;
        __syncthreads();
#pragma unroll
        for (int k = 0; k < 16; ++k) {
            float av0 = As[k][ty], av1 = As[k][ty + 16];
            float bv0 = Bs[k][tx], bv1 = Bs[k][tx + 16];
            c00 += av0 * bv0;  c01 += av0 * bv1;
            c10 += av1 * bv0;  c11 += av1 * bv1;
        }
        aptr += 16; wptr += 16;
    }

    int r0 = m0 + ty, r1 = m0 + ty + 16;
    int cc0 = n0 + tx, cc1 = n0 + tx + 16;
    float accv[2][2] = {{c00, c01}, {c10, c11}};
    int rows[2] = {r0, r1};
    int cols[2] = {cc0, cc1};
#pragma unroll
    for (int i = 0; i < 2; ++i)
#pragma unroll
        for (int j = 0; j < 2; ++j) {
            int c = cols[j];
            if (c < N) {
                size_t idx = (size_t)rows[i] * N + c;
                float v = accv[i][j];
                if (accumulate) v += Cm[idx];
                if (bias0) v += bias0[c];
                if (bias1) v += bias1[c];
                if (act == 1) v = tanhf(v);
                Cm[idx] = v;
            }
        }
}

// ---------------- LSTM pointwise: c = sig(i)*tanh(g); h = sig(o)*tanh(c) ----------------
__global__ __launch_bounds__(256)
void lstm_h_kernel(const float* __restrict__ G, float* __restrict__ hbuf,
                   float* __restrict__ dec_in)
{
    int idx = blockIdx.x * 256 + threadIdx.x;     // 256*512
    int b = idx >> 9, j = idx & 511;
    const float* g = G + (size_t)b * 2048;
    float ig = g[j], gg = g[1024 + j], og = g[1536 + j];
    float si = 1.f / (1.f + expf(-ig));
    float so = 1.f / (1.f + expf(-og));
    float c  = si * tanhf(gg);
    float h  = so * tanhf(c);
    hbuf[idx] = h;
    dec_in[(size_t)b * FC1_IN + A_DIM + j] = h;
}

// ---------------- attention = v * softmax(e) per row ----------------
__global__ __launch_bounds__(256)
void att_kernel(const float* __restrict__ e, const float* __restrict__ vvec,
                float* __restrict__ att)
{
    __shared__ float s_ex[A_DIM];
    __shared__ float red[256];
    int b = blockIdx.x, t = threadIdx.x;
    const float* er = e + (size_t)b * A_DIM;
    float local = 0.f;
    for (int a = t; a < A_DIM; a += 256) {
        float ex = expf(er[a]);     // |e|<1 after tanh: no max-sub needed
        s_ex[a] = ex; local += ex;
    }
    red[t] = local; __syncthreads();
    for (int s = 128; s > 0; s >>= 1) {
        if (t < s) red[t] += red[t + s];
        __syncthreads();
    }
    float inv = 1.f / red[0];
    for (int a = t; a < A_DIM; a += 256)
        att[(size_t)b * A_DIM + a] = vvec[a] * s_ex[a] * inv;
}

// ---------------- context = att @ enc  (+ gen reduction) ----------------
__global__ __launch_bounds__(512)
void ctx_gen_kernel(const float* __restrict__ att, const float* __restrict__ enc,
                    const float* __restrict__ x, const float* __restrict__ h,
                    const float* __restrict__ pg1, const float* __restrict__ pg2,
                    const float* __restrict__ pg3,
                    float* __restrict__ dec_in, float* __restrict__ gen)
{
    __shared__ float s_att[A_DIM];
    __shared__ float red[512];
    int b = blockIdx.x, t = threadIdx.x;
    for (int a = t; a < A_DIM; a += 512) s_att[a] = att[(size_t)b * A_DIM + a];
    __syncthreads();
    float acc = 0.f;
    if (t < A_DIM) {
        const float* ep = enc + (size_t)b * (A_DIM * A_DIM) + t;
#pragma unroll 4
        for (int a = 0; a < A_DIM; ++a) acc += s_att[a] * ep[(size_t)a * A_DIM];
        dec_in[(size_t)b * FC1_IN + t] = acc;
    }
    float local = 0.f;
    if (t < A_DIM) local += acc * pg2[t];
    if (t < I_DIM) local += x[(size_t)b * I_DIM + t] * pg1[t];
    local += h[(size_t)b * H_DIM + t] * pg3[t];     // t < 512 always
    red[t] = local; __syncthreads();
    for (int s = 256; s > 0; s >>= 1) {
        if (t < s) red[t] += red[t + s];
        __syncthreads();
    }
    if (t == 0) gen[b] = 1.f / (1.f + expf(-red[0]));
}

// ---------------- hid fp32 -> bf16 ----------------
__global__ __launch_bounds__(256)
void cvt_kernel(const float* __restrict__ hid, u16* __restrict__ hb)
{
    int idx = blockIdx.x * 256 + threadIdx.x;     // 256*1024
    hb[idx] = f2bf(hid[idx]);
}

// ---------------- fc2 via bf16 MFMA + exp + row-sum atomics ----------------
// 512 thr = 8 waves; block tile = 256 rows x 64 cols; K=1024, BK=64, 16 phases.
// DISTANCE-2 REGISTER PIPELINE: phase kt issues W loads for tile kt+2 (regset kt&1),
// cvt+ds_writes tile kt+1 (regset (kt+1)&1, loaded 2 phases ago -> HBM latency
// covered by ~2 full phases), ds_read+MFMA tile kt. Raw s_barrier with ONLY
// lgkmcnt(0) -- __syncthreads' implicit vmcnt(0) drain was the round-1 convoy
// (no load could survive a phase boundary -> one HBM latency per phase).
// Buffers: phase A reads buf0/writes buf1, phase B reverse; one barrier between
// any read and the write that overwrites it => race-free. Two-phase body written
// manually so prefetch regs have static indices (no scratch spill).
__global__ __launch_bounds__(512)
void fc2_kernel(const u16* __restrict__ hb, const float* __restrict__ W,
                const float* __restrict__ bias, float* __restrict__ out,
                float* __restrict__ sums)
{
    __shared__ __align__(16) u16 Ws[2][64][72];   // [buf][n][k], +8 pad
    int t = threadIdx.x;
    int wv = t >> 6, lane = t & 63;               // wv 0..7
    int lm = lane & 15, lk = lane >> 4;           // 0..15, 0..3
    int n0 = blockIdx.x * 64;
    int row_base = wv * 32;

    float4_ acc[2][4];
#pragma unroll
    for (int mi = 0; mi < 2; ++mi)
#pragma unroll
        for (int ni = 0; ni < 4; ++ni)
            acc[mi][ni] = (float4_){0.f, 0.f, 0.f, 0.f};

    int sn = t >> 3;             // staging row 0..63
    int sk = (t & 7) * 8;        // k-offset 0,8,..,56
    bool svalid = (n0 + sn) < V_DIM;
    const float* wsrc = W + (size_t)(n0 + sn) * FC2_K + sk;

    const u16* a0 = hb + (size_t)(row_base + lm) * FC2_K + lk * 8;
    const u16* a1 = a0 + (size_t)16 * FC2_K;

    const float4_ z = (float4_){0.f, 0.f, 0.f, 0.f};
    float4_ pwa0, pwa1;   // regset 0: even tiles
    float4_ pwb0, pwb1;   // regset 1: odd tiles

    // ---- prologue: load tiles 0 and 1; cvt+write tile 0 -> buf0 ----
    {
        const float4_* p0 = (const float4_*)(wsrc);
        const float4_* p1 = (const float4_*)(wsrc + 64);
        pwa0 = svalid ? p0[0] : z;  pwa1 = svalid ? p0[1] : z;
        pwb0 = svalid ? p1[0] : z;  pwb1 = svalid ? p1[1] : z;
    }
    *(short8*)&Ws[0][sn][sk] = cvt_pack8(pwa0, pwa1);
    asm volatile("s_waitcnt lgkmcnt(0)\n\ts_barrier" ::: "memory");

#pragma unroll 1
    for (int j = 0; j < 8; ++j) {
        // ================= phase A: tile 2j (buf0), stage tile 2j+1 -> buf1 =====
        {
            int kt = 2 * j;
            if (j < 7) {   // load tile kt+2 into regset 0
                const float4_* p = (const float4_*)(wsrc + (kt + 2) * 64);
                pwa0 = svalid ? p[0] : z;
                pwa1 = svalid ? p[1] : z;
            }
            int kb = kt * 64;
            short8 af00 = *(const short8*)(a0 + kb);
            short8 af01 = *(const short8*)(a0 + kb + 32);
            short8 af10 = *(const short8*)(a1 + kb);
            short8 af11 = *(const short8*)(a1 + kb + 32);
            // cvt+write tile kt+1 (regset 1, loaded 2 phases ago) -> buf1
            *(short8*)&Ws[1][sn][sk] = cvt_pack8(pwb0, pwb1);
#pragma unroll
            for (int ks = 0; ks < 2; ++ks) {
                short8 bfr[4];
#pragma unroll
                for (int ni = 0; ni < 4; ++ni)
                    bfr[ni] = *(const short8*)&Ws[0][ni * 16 + lm][ks * 32 + lk * 8];
                short8 afp0 = ks ? af01 : af00;
                short8 afp1 = ks ? af11 : af10;
#pragma unroll
                for (int ni = 0; ni < 4; ++ni) {
                    acc[0][ni] = __builtin_amdgcn_mfma_f32_16x16x32_bf16(afp0, bfr[ni], acc[0][ni], 0, 0, 0);
                    acc[1][ni] = __builtin_amdgcn_mfma_f32_16x16x32_bf16(afp1, bfr[ni], acc[1][ni], 0, 0, 0);
                }
            }
            asm volatile("s_waitcnt lgkmcnt(0)\n\ts_barrier" ::: "memory");
        }
        // ================= phase B: tile 2j+1 (buf1), stage tile 2j+2 -> buf0 ===
        {
            int kt = 2 * j + 1;
            if (j < 7) {   // load tile kt+2 into regset 1
                const float4_* p = (const float4_*)(wsrc + (kt + 2) * 64);
                pwb0 = svalid ? p[0] : z;
                pwb1 = svalid ? p[1] : z;
            }
            int kb = kt * 64;
            short8 af00 = *(const short8*)(a0 + kb);
            short8 af01 = *(const short8*)(a0 + kb + 32);
            short8 af10 = *(const short8*)(a1 + kb);
            short8 af11 = *(const short8*)(a1 + kb + 32);
            // cvt+write tile kt+1 (regset 0) -> buf0 (skip on last super-iter)
            if (j < 7)
                *(short8*)&Ws[0][sn][sk] = cvt_pack8(pwa0, pwa1);
#pragma unroll
            for (int ks = 0; ks < 2; ++ks) {
                short8 bfr[4];
#pragma unroll
                for (int ni = 0; ni < 4; ++ni)
                    bfr[ni] = *(const short8*)&Ws[1][ni * 16 + lm][ks * 32 + lk * 8];
                short8 afp0 = ks ? af01 : af00;
                short8 afp1 = ks ? af11 : af10;
#pragma unroll
                for (int ni = 0; ni < 4; ++ni) {
                    acc[0][ni] = __builtin_amdgcn_mfma_f32_16x16x32_bf16(afp0, bfr[ni], acc[0][ni], 0, 0, 0);
                    acc[1][ni] = __builtin_amdgcn_mfma_f32_16x16x32_bf16(afp1, bfr[ni], acc[1][ni], 0, 0, 0);
                }
            }
            asm volatile("s_waitcnt lgkmcnt(0)\n\ts_barrier" ::: "memory");
        }
    }

    // Epilogue: logit = acc + bias; e = exp(logit); store; row-sum via shfl + atomic.
#pragma unroll
    for (int mi = 0; mi < 2; ++mi) {
        int r_base = row_base + mi * 16 + lk * 4;   // rows r_base..r_base+3
        float s[4] = {0.f, 0.f, 0.f, 0.f};
#pragma unroll
        for (int ni = 0; ni < 4; ++ni) {
            int col = n0 + ni * 16 + lm;
            if (col < V_DIM) {
                float bcol = bias[col];
                float4_ a = acc[mi][ni];
#pragma unroll
                for (int r = 0; r < 4; ++r) {
                    float ev = expf(a[r] + bcol);
                    out[(size_t)(r_base + r) * VP + col] = ev;
                    s[r] += ev;
                }
            }
        }
#pragma unroll
        for (int off = 1; off < 16; off <<= 1) {
#pragma unroll
            for (int r = 0; r < 4; ++r) s[r] += __shfl_xor(s[r], off);
        }
        if (lm == 0) {
#pragma unroll
            for (int r = 0; r < 4; ++r) atomicAdd(&sums[r_base + r], s[r]);
        }
    }
}

// ---------------- out = gen/sum * exp ; zero OOV tail ----------------
__global__ __launch_bounds__(256)
void rescale_kernel(float* __restrict__ out, const float* __restrict__ gen,
                    const float* __restrict__ sums)
{
    int idx = (blockIdx.x * 256 + threadIdx.x) * 2;   // total 256*50050, even
    int b = idx / VP;
    int c = idx - b * VP;
    float2 v = *(float2*)(out + idx);
    float scale = gen[b] / sums[b];
    v.x = (c     < V_DIM) ? v.x * scale : 0.f;
    v.y = (c + 1 < V_DIM) ? v.y * scale : 0.f;
    *(float2*)(out + idx) = v;
}

// ---------------- scatter: out[b, ids[b,a]] += (1-gen[b]) * att[b,a] ----------------
__global__ __launch_bounds__(256)
void scatter_kernel(const int* __restrict__ ids, const float* __restrict__ att,
                    const float* __restrict__ gen, float* __restrict__ out)
{
    int idx = blockIdx.x * 256 + threadIdx.x;   // 256*400
    int b = idx / A_DIM;
    float val = (1.f - gen[b]) * att[idx];
    atomicAdd(out + (size_t)b * VP + ids[idx], val);
}

extern "C" void kernel_launch(void* const* d_in, const int* in_sizes, int n_in,
                              void* d_out, int out_size, void* d_ws, size_t ws_size,
                              hipStream_t stream)
{
    const float* x         = (const float*)d_in[0];
    const float* enc       = (const float*)d_in[2];
    const float* enc_state = (const float*)d_in[4];
    const int*   ids       = (const int*)  d_in[6];
    const float* W_ih      = (const float*)d_in[7];
    const float* b_ih      = (const float*)d_in[9];
    const float* b_hh      = (const float*)d_in[10];
    const float* Wh_w      = (const float*)d_in[11];
    const float* Wh_b      = (const float*)d_in[12];
    const float* Ws_w      = (const float*)d_in[13];
    const float* Ws_b      = (const float*)d_in[14];
    const float* vvec      = (const float*)d_in[15];
    const float* fc1_w     = (const float*)d_in[16];
    const float* fc1_b     = (const float*)d_in[17];
    const float* fc2_w     = (const float*)d_in[18];
    const float* fc2_b     = (const float*)d_in[19];
    const float* pg1       = (const float*)d_in[20];
    const float* pg2       = (const float*)d_in[21];
    const float* pg3       = (const float*)d_in[22];
    float* out = (float*)d_out;

    float* ws    = (float*)d_ws;
    float* gates = ws;                        // 256*2048
    float* hbuf  = gates + 256 * 2048;        // 256*512
    float* ebuf  = hbuf  + 256 * 512;         // 256*400
    float* attb  = ebuf  + 256 * 400;         // 256*400
    float* dec   = attb  + 256 * 400;         // 256*912
    float* hid   = dec   + 256 * 912;         // 256*1024
    float* genb  = hid   + 256 * 1024;        // 256
    float* sums  = genb  + 256;               // 256
    u16*   hbf   = (u16*)(sums + 256);        // 256*1024 bf16

    // gates = x0 @ W_ih^T + b_ih + b_hh
    sgemm32<<<dim3(64, 8), 256, 0, stream>>>(x, W_ih, gates, b_ih, b_hh,
                                             BB, 2048, I_DIM, 0, 0);
    // h
    lstm_h_kernel<<<512, 256, 0, stream>>>(gates, hbuf, dec);
    // e = tanh(ES@Wh^T + Wh_b + h@Ws^T + Ws_b)
    sgemm32<<<dim3(13, 8), 256, 0, stream>>>(enc_state, Wh_w, ebuf, Wh_b, nullptr,
                                             BB, A_DIM, H_DIM, 0, 0);
    sgemm32<<<dim3(13, 8), 256, 0, stream>>>(hbuf, Ws_w, ebuf, Ws_b, nullptr,
                                             BB, A_DIM, H_DIM, 1, 1);
    // attention
    att_kernel<<<BB, 256, 0, stream>>>(ebuf, vvec, attb);
    // context + gen
    ctx_gen_kernel<<<BB, 512, 0, stream>>>(attb, enc, x, hbuf, pg1, pg2, pg3,
                                           dec, genb);
    // fc1
    sgemm32<<<dim3(32, 8), 256, 0, stream>>>(dec, fc1_w, hid, fc1_b, nullptr,
                                             BB, FC1_OUT, FC1_IN, 0, 0);
    // hid -> bf16
    cvt_kernel<<<1024, 256, 0, stream>>>(hid, hbf);
    // zero row sums
    hipMemsetAsync(sums, 0, BB * sizeof(float), stream);
    // fc2 + exp + row sums  (782 = ceil(50000/64))
    fc2_kernel<<<782, 512, 0, stream>>>(hbf, fc2_w, fc2_b, out, sums);
    // scale by gen/sum, zero OOV tail
    rescale_kernel<<<(BB * VP) / 512, 256, 0, stream>>>(out, genb, sums);
    // pointer-copy scatter
    scatter_kernel<<<(BB * A_DIM) / 256, 256, 0, stream>>>(ids, attb, genb, out);
}